// Round 2
// baseline (15675.481 us; speedup 1.0000x reference)
//
#include <hip/hip_runtime.h>
#include <math.h>

#define TS 43      // tokens per sample (1 + 6*7)
#define DD 128
#define NH 4
#define DKK 32
#define DFFN 512
#define NLAY 4
#define STR 132    // padded row stride (words) for [TS][DD] tiles
#define GSTR 516   // padded row stride for ffn intermediate [TS][512]
#define NBUCK 143
#define PSTR 44

struct SmemT {
  float xb[TS][STR];   // residual stream
  float yb[TS][STR];   // LN output / scratch
  union {
    struct { float qb[TS][STR]; float kb[TS][STR]; float vb[TS][STR];
             float probs[NH][TS][PSTR]; } a;
    struct { float gbuf[TS][GSTR]; } f;
  } u;
  float bias[NH][NBUCK + 1];
  int bucket[TS][PSTR];
};

__device__ __forceinline__ float wsum(float v) {
  #pragma unroll
  for (int m = 32; m >= 1; m >>= 1) v += __shfl_xor(v, m, 64);
  return v;
}
__device__ __forceinline__ float wmax(float v) {
  #pragma unroll
  for (int m = 32; m >= 1; m >>= 1) v = fmaxf(v, __shfl_xor(v, m, 64));
  return v;
}
__device__ __forceinline__ float gelu_exact(float x) {
  return 0.5f * x * (1.0f + erff(x * 0.70710678118654752f));
}

__global__ __launch_bounds__(256, 1)
void tdqn_fused(const int* __restrict__ board, const int* __restrict__ ptm_arr,
                const int* __restrict__ bucket_index,
                const float* __restrict__ cell_emb, const float* __restrict__ player_emb,
                const float* __restrict__ cls_token, const float* __restrict__ bias_table,
                const float* __restrict__ ln1_s, const float* __restrict__ ln1_b,
                const float* __restrict__ Wq, const float* __restrict__ bq,
                const float* __restrict__ Wk, const float* __restrict__ bk,
                const float* __restrict__ Wv, const float* __restrict__ bv,
                const float* __restrict__ Wo, const float* __restrict__ bo,
                const float* __restrict__ ln2_s, const float* __restrict__ ln2_b,
                const float* __restrict__ W1, const float* __restrict__ b1,
                const float* __restrict__ W2, const float* __restrict__ b2,
                const float* __restrict__ lnf_s, const float* __restrict__ lnf_b,
                const float* __restrict__ Whead, const float* __restrict__ bhead,
                float* __restrict__ out, int nB)
{
  __shared__ SmemT sm;
  const int b = blockIdx.x;
  const int tid = threadIdx.x;
  const int lane = tid & 63;
  const int wave = tid >> 6;
  const int g = wave;        // row group for GEMM mappings
  const int d0 = tid & 63;   // column lane for GEMM mappings

  // ---- stage bucket table + bias table ----
  for (int idx = tid; idx < TS * TS; idx += 256)
    sm.bucket[idx / TS][idx % TS] = bucket_index[idx];
  for (int idx = tid; idx < NH * NBUCK; idx += 256)
    sm.bias[idx / NBUCK][idx % NBUCK] = bias_table[idx];

  // ---- embeddings ----
  const int ptm = ptm_arr[b];
  for (int idx = tid; idx < TS * DD; idx += 256) {
    int t = idx >> 7, d = idx & 127;
    float v;
    if (t == 0) v = cls_token[d] + player_emb[ptm * DD + d];
    else        v = cell_emb[board[b * 42 + (t - 1)] * DD + d];
    sm.xb[t][d] = v;
  }
  __syncthreads();

  // generic 43x128 @ 128x128 projection: each thread owns cols (d0, d0+64),
  // rows t = g + 4j. W streamed from global, activations broadcast from LDS.
  auto proj128 = [&](const float (*src)[STR], const float* W, const float* bias,
                     float (*dst)[STR], bool add_into) {
    float acc0[11], acc1[11];
    #pragma unroll
    for (int j = 0; j < 11; ++j) { acc0[j] = 0.f; acc1[j] = 0.f; }
    const int c0 = d0, c1 = d0 + 64;
    for (int kk = 0; kk < DD; kk += 4) {
      float w00 = W[(kk + 0) * DD + c0], w01 = W[(kk + 0) * DD + c1];
      float w10 = W[(kk + 1) * DD + c0], w11 = W[(kk + 1) * DD + c1];
      float w20 = W[(kk + 2) * DD + c0], w21 = W[(kk + 2) * DD + c1];
      float w30 = W[(kk + 3) * DD + c0], w31 = W[(kk + 3) * DD + c1];
      #pragma unroll
      for (int j = 0; j < 11; ++j) {
        int t = g + 4 * j;
        if (t < TS) {
          float4 y4 = *(const float4*)&src[t][kk];
          acc0[j] += y4.x * w00 + y4.y * w10 + y4.z * w20 + y4.w * w30;
          acc1[j] += y4.x * w01 + y4.y * w11 + y4.z * w21 + y4.w * w31;
        }
      }
    }
    #pragma unroll
    for (int j = 0; j < 11; ++j) {
      int t = g + 4 * j;
      if (t < TS) {
        if (add_into) {
          dst[t][c0] += acc0[j] + bias[c0];
          dst[t][c1] += acc1[j] + bias[c1];
        } else {
          dst[t][c0] = acc0[j] + bias[c0];
          dst[t][c1] = acc1[j] + bias[c1];
        }
      }
    }
  };

  auto layer_norm = [&](const float (*src)[STR], float (*dst)[STR],
                        const float* s, const float* bb) {
    for (int t = wave; t < TS; t += 4) {
      float a0 = src[t][lane], a1 = src[t][lane + 64];
      float sum = wsum(a0 + a1);
      float sq  = wsum(a0 * a0 + a1 * a1);
      float mu  = sum * (1.0f / 128.0f);
      float var = sq * (1.0f / 128.0f) - mu * mu;
      float r   = rsqrtf(var + 1e-5f);
      dst[t][lane]      = (a0 - mu) * r * s[lane]      + bb[lane];
      dst[t][lane + 64] = (a1 - mu) * r * s[lane + 64] + bb[lane + 64];
    }
  };

  for (int l = 0; l < NLAY; ++l) {
    // ---- LN1 ----
    layer_norm(sm.xb, sm.yb, ln1_s + l * DD, ln1_b + l * DD);
    __syncthreads();

    // ---- Q,K,V projections ----
    proj128(sm.yb, Wq + l * DD * DD, bq + l * DD, sm.u.a.qb, false);
    proj128(sm.yb, Wk + l * DD * DD, bk + l * DD, sm.u.a.kb, false);
    proj128(sm.yb, Wv + l * DD * DD, bv + l * DD, sm.u.a.vb, false);
    __syncthreads();

    // ---- scores + softmax: wave = head, lane = key index ----
    {
      const int h = wave, hoff = h * DKK;
      const int jl = (lane < TS) ? lane : 0;
      float kreg[DKK];
      #pragma unroll
      for (int d = 0; d < DKK; ++d) kreg[d] = sm.u.a.kb[jl][hoff + d];
      const float scl = 0.17677669529663687f;  // 1/sqrt(32)
      for (int i = 0; i < TS; ++i) {
        float acc = 0.f;
        #pragma unroll
        for (int dd = 0; dd < DKK / 4; ++dd) {
          float4 q4 = *(const float4*)&sm.u.a.qb[i][hoff + dd * 4];
          acc += q4.x * kreg[dd * 4] + q4.y * kreg[dd * 4 + 1]
               + q4.z * kreg[dd * 4 + 2] + q4.w * kreg[dd * 4 + 3];
        }
        float sc = acc * scl + sm.bias[h][sm.bucket[i][jl]];
        if (lane >= TS) sc = -1e30f;
        float m = wmax(sc);
        float e = (lane < TS) ? expf(sc - m) : 0.f;
        float ssum = wsum(e);
        float p = e / ssum;
        if (lane < PSTR) sm.u.a.probs[h][i][lane] = (lane < TS) ? p : 0.f;
      }
    }
    __syncthreads();

    // ---- P @ V -> attn (written into kb's columns for this head) ----
    {
      const int h = wave, hoff = h * DKK;
      const int d4 = (lane & 7) * 4;
      const int isub = lane >> 3;
      for (int i = isub; i < TS; i += 8) {
        float4 acc = make_float4(0.f, 0.f, 0.f, 0.f);
        for (int j = 0; j < PSTR; j += 4) {
          float4 p4 = *(const float4*)&sm.u.a.probs[h][i][j];
          float4 v0 = *(const float4*)&sm.u.a.vb[j + 0][hoff + d4];
          float4 v1 = *(const float4*)&sm.u.a.vb[j + 1][hoff + d4];
          float4 v2 = *(const float4*)&sm.u.a.vb[j + 2][hoff + d4];
          float4 v3 = *(const float4*)&sm.u.a.vb[j + 3][hoff + d4];
          acc.x += p4.x * v0.x + p4.y * v1.x + p4.z * v2.x + p4.w * v3.x;
          acc.y += p4.x * v0.y + p4.y * v1.y + p4.z * v2.y + p4.w * v3.y;
          acc.z += p4.x * v0.z + p4.y * v1.z + p4.z * v2.z + p4.w * v3.z;
          acc.w += p4.x * v0.w + p4.y * v1.w + p4.z * v2.w + p4.w * v3.w;
        }
        *(float4*)&sm.u.a.kb[i][hoff + d4] = acc;
      }
    }
    __syncthreads();

    // ---- O projection + residual into xb ----
    proj128(sm.u.a.kb, Wo + l * DD * DD, bo + l * DD, sm.xb, true);
    __syncthreads();

    // ---- LN2 ----
    layer_norm(sm.xb, sm.yb, ln2_s + l * DD, ln2_b + l * DD);
    __syncthreads();

    // ---- FFN stage A: gbuf = gelu(yb @ W1 + b1) ----
    {
      const float* W1l = W1 + l * DD * DFFN;
      const float* b1l = b1 + l * DFFN;
      for (int cc = 0; cc < 4; ++cc) {
        const int c0 = d0 + cc * 128, c1 = c0 + 64;
        float acc0[11], acc1[11];
        #pragma unroll
        for (int j = 0; j < 11; ++j) { acc0[j] = 0.f; acc1[j] = 0.f; }
        for (int kk = 0; kk < DD; kk += 4) {
          float w00 = W1l[(kk + 0) * DFFN + c0], w01 = W1l[(kk + 0) * DFFN + c1];
          float w10 = W1l[(kk + 1) * DFFN + c0], w11 = W1l[(kk + 1) * DFFN + c1];
          float w20 = W1l[(kk + 2) * DFFN + c0], w21 = W1l[(kk + 2) * DFFN + c1];
          float w30 = W1l[(kk + 3) * DFFN + c0], w31 = W1l[(kk + 3) * DFFN + c1];
          #pragma unroll
          for (int j = 0; j < 11; ++j) {
            int t = g + 4 * j;
            if (t < TS) {
              float4 y4 = *(const float4*)&sm.yb[t][kk];
              acc0[j] += y4.x * w00 + y4.y * w10 + y4.z * w20 + y4.w * w30;
              acc1[j] += y4.x * w01 + y4.y * w11 + y4.z * w21 + y4.w * w31;
            }
          }
        }
        #pragma unroll
        for (int j = 0; j < 11; ++j) {
          int t = g + 4 * j;
          if (t < TS) {
            sm.u.f.gbuf[t][c0] = gelu_exact(acc0[j] + b1l[c0]);
            sm.u.f.gbuf[t][c1] = gelu_exact(acc1[j] + b1l[c1]);
          }
        }
      }
    }
    __syncthreads();

    // ---- FFN stage B: xb += gbuf @ W2 + b2 ----
    {
      const float* W2l = W2 + l * DFFN * DD;
      const float* b2l = b2 + l * DD;
      const int c0 = d0, c1 = d0 + 64;
      float acc0[11], acc1[11];
      #pragma unroll
      for (int j = 0; j < 11; ++j) { acc0[j] = 0.f; acc1[j] = 0.f; }
      for (int f = 0; f < DFFN; f += 4) {
        float w00 = W2l[(f + 0) * DD + c0], w01 = W2l[(f + 0) * DD + c1];
        float w10 = W2l[(f + 1) * DD + c0], w11 = W2l[(f + 1) * DD + c1];
        float w20 = W2l[(f + 2) * DD + c0], w21 = W2l[(f + 2) * DD + c1];
        float w30 = W2l[(f + 3) * DD + c0], w31 = W2l[(f + 3) * DD + c1];
        #pragma unroll
        for (int j = 0; j < 11; ++j) {
          int t = g + 4 * j;
          if (t < TS) {
            float4 g4 = *(const float4*)&sm.u.f.gbuf[t][f];
            acc0[j] += g4.x * w00 + g4.y * w10 + g4.z * w20 + g4.w * w30;
            acc1[j] += g4.x * w01 + g4.y * w11 + g4.z * w21 + g4.w * w31;
          }
        }
      }
      #pragma unroll
      for (int j = 0; j < 11; ++j) {
        int t = g + 4 * j;
        if (t < TS) {
          sm.xb[t][c0] += acc0[j] + b2l[c0];
          sm.xb[t][c1] += acc1[j] + b2l[c1];
        }
      }
    }
    __syncthreads();
  }

  // ---- final LN (token 0 only) ----
  if (wave == 0) {
    float a0 = sm.xb[0][lane], a1 = sm.xb[0][lane + 64];
    float sum = wsum(a0 + a1);
    float sq  = wsum(a0 * a0 + a1 * a1);
    float mu  = sum * (1.0f / 128.0f);
    float var = sq * (1.0f / 128.0f) - mu * mu;
    float r   = rsqrtf(var + 1e-5f);
    sm.yb[0][lane]      = (a0 - mu) * r * lnf_s[lane]      + lnf_b[lane];
    sm.yb[0][lane + 64] = (a1 - mu) * r * lnf_s[lane + 64] + lnf_b[lane + 64];
  }
  __syncthreads();

  // ---- head + masking ----
  if (tid < 7) {
    const int c = tid;
    float acc = bhead[c];
    for (int d = 0; d < DD; ++d) acc += sm.yb[0][d] * Whead[d * 7 + c];
    const int ob = b * 7 + c;
    const bool valid = (board[b * 42 + c] == 0);  // board row 0
    out[ob] = acc;
    out[nB * 7 + ob] = valid ? acc : -1e9f;
    out[2 * nB * 7 + ob] = valid ? 1.0f : 0.0f;
  }
}

extern "C" void kernel_launch(void* const* d_in, const int* in_sizes, int n_in,
                              void* d_out, int out_size, void* d_ws, size_t ws_size,
                              hipStream_t stream) {
  const int*   board      = (const int*)d_in[0];
  const int*   ptm        = (const int*)d_in[1];
  const int*   bucket_idx = (const int*)d_in[2];
  const float* cell_emb   = (const float*)d_in[3];
  const float* player_emb = (const float*)d_in[4];
  const float* cls_token  = (const float*)d_in[5];
  const float* bias_table = (const float*)d_in[6];
  const float* ln1_s      = (const float*)d_in[7];
  const float* ln1_b      = (const float*)d_in[8];
  const float* Wq         = (const float*)d_in[9];
  const float* bq         = (const float*)d_in[10];
  const float* Wk         = (const float*)d_in[11];
  const float* bk         = (const float*)d_in[12];
  const float* Wv         = (const float*)d_in[13];
  const float* bv         = (const float*)d_in[14];
  const float* Wo         = (const float*)d_in[15];
  const float* bo         = (const float*)d_in[16];
  const float* ln2_s      = (const float*)d_in[17];
  const float* ln2_b      = (const float*)d_in[18];
  const float* W1         = (const float*)d_in[19];
  const float* b1         = (const float*)d_in[20];
  const float* W2         = (const float*)d_in[21];
  const float* b2         = (const float*)d_in[22];
  const float* lnf_s      = (const float*)d_in[23];
  const float* lnf_b      = (const float*)d_in[24];
  const float* Whead      = (const float*)d_in[25];
  const float* bhead      = (const float*)d_in[26];

  const int nB = in_sizes[1];  // 4096
  float* out = (float*)d_out;

  hipLaunchKernelGGL(tdqn_fused, dim3(nB), dim3(256), 0, stream,
                     board, ptm, bucket_idx, cell_emb, player_emb, cls_token,
                     bias_table, ln1_s, ln1_b, Wq, bq, Wk, bk, Wv, bv, Wo, bo,
                     ln2_s, ln2_b, W1, b1, W2, b2, lnf_s, lnf_b, Whead, bhead,
                     out, nB);
}

// Round 5
// 2256.837 us; speedup vs baseline: 6.9458x; 6.9458x over previous
//
#include <hip/hip_runtime.h>
#include <math.h>

#define TS 43      // tokens per sample (1 + 6*7)
#define DD 128
#define NH 4
#define DFFN 512
#define NLAY 4

typedef __bf16 bf16x8_t __attribute__((ext_vector_type(8)));
typedef float  f32x4_t  __attribute__((ext_vector_type(4)));

#define MFMA16(a, b, c) __builtin_amdgcn_mfma_f32_16x16x32_bf16((a), (b), (c), 0, 0, 0)

// LDS layout. All fragment-read buffers have 16B-aligned row strides.
struct __align__(16) SmemT {
  float  xb[48][132];            // residual stream, f32
  __bf16 yb[48][136];            // LN output (MFMA A input)
  union {
    struct {
      __bf16 Qb[48][136];        // Q (A-operand for QK^T)
      __bf16 Kb[48][136];        // K (B-operand for QK^T); reused for attn-out
      __bf16 Vt[128][72];        // V transposed: Vt[d][token] (B-operand for PV)
      __bf16 P[NH][48][72];      // probs per head (A-operand for PV)
    } a;
    struct { __bf16 gbuf[48][520]; } f;   // FFN intermediate
  } u;
  float bias[NH][144];
  int   bucket[TS][44];
};

__device__ __forceinline__ float wsum(float v) {
  #pragma unroll
  for (int m = 32; m >= 1; m >>= 1) v += __shfl_xor(v, m, 64);
  return v;
}
__device__ __forceinline__ float red16max(float v) {
  #pragma unroll
  for (int m = 8; m >= 1; m >>= 1) v = fmaxf(v, __shfl_xor(v, m, 64));
  return v;
}
__device__ __forceinline__ float red16sum(float v) {
  #pragma unroll
  for (int m = 8; m >= 1; m >>= 1) v += __shfl_xor(v, m, 64);
  return v;
}
__device__ __forceinline__ float gelu_exact(float x) {
  return 0.5f * x * (1.0f + erff(x * 0.70710678118654752f));
}

// ---- weight prep: f32 [K][N] -> bf16 W^T [N][K] in d_ws ----
// layout (elements): [0)      4x4x16384  WqT,WkT,WvT,WoT (type-major, layer inner)
//                    [262144) 4x 512x128 W1T
//                    [524288) 4x 128x512 W2T
__global__ void prep_weights(const float* __restrict__ Wq, const float* __restrict__ Wk,
                             const float* __restrict__ Wv, const float* __restrict__ Wo,
                             const float* __restrict__ W1, const float* __restrict__ W2,
                             __bf16* __restrict__ ws) {
  int idx = blockIdx.x * 256 + threadIdx.x;
  if (idx < 262144) {
    int t = idx >> 16;            // 0..3 : q,k,v,o
    int rem = idx & 65535;
    int l = rem >> 14;
    int r2 = rem & 16383;
    int n = r2 >> 7, k = r2 & 127;
    const float* W = (t == 0) ? Wq : (t == 1) ? Wk : (t == 2) ? Wv : Wo;
    ws[idx] = (__bf16)W[l * 16384 + k * 128 + n];
  } else if (idx < 524288) {
    int rem = idx - 262144;       // W1T: [512][128] per layer
    int l = rem >> 16;
    int r2 = rem & 65535;
    int n = r2 >> 7, k = r2 & 127;
    ws[idx] = (__bf16)W1[l * 65536 + k * 512 + n];
  } else if (idx < 786432) {
    int rem = idx - 524288;       // W2T: [128][512] per layer
    int l = rem >> 16;
    int r2 = rem & 65535;
    int n = r2 >> 9, f = r2 & 511;
    ws[idx] = (__bf16)W2[l * 65536 + f * 128 + n];
  }
}

__global__ __launch_bounds__(256, 1)
void tdqn_fused(const int* __restrict__ board, const int* __restrict__ ptm_arr,
                const int* __restrict__ bucket_index,
                const float* __restrict__ cell_emb, const float* __restrict__ player_emb,
                const float* __restrict__ cls_token, const float* __restrict__ bias_table,
                const float* __restrict__ ln1_s, const float* __restrict__ ln1_b,
                const float* __restrict__ bq, const float* __restrict__ bk,
                const float* __restrict__ bv, const float* __restrict__ bo,
                const float* __restrict__ ln2_s, const float* __restrict__ ln2_b,
                const float* __restrict__ b1, const float* __restrict__ b2,
                const float* __restrict__ lnf_s, const float* __restrict__ lnf_b,
                const float* __restrict__ Whead, const float* __restrict__ bhead,
                const __bf16* __restrict__ ws,
                float* __restrict__ out, int nB)
{
  __shared__ SmemT sm;
  const int b = blockIdx.x;
  const int tid = threadIdx.x;
  const int lane = tid & 63;
  const int wave = tid >> 6;
  const int l15 = lane & 15;
  const int hi8 = (lane >> 4) * 8;   // k-offset within fragment
  const int hi4 = (lane >> 4) * 4;   // row-offset within D tile

  // ---- stage bucket + bias tables ----
  for (int idx = tid; idx < TS * TS; idx += 256)
    sm.bucket[idx / TS][idx % TS] = bucket_index[idx];
  for (int idx = tid; idx < NH * 143; idx += 256)
    sm.bias[idx / 143][idx % 143] = bias_table[idx];

  // ---- embeddings (f32 residual) ----
  const int ptm = ptm_arr[b];
  for (int idx = tid; idx < TS * DD; idx += 256) {
    int t = idx >> 7, d = idx & 127;
    float v;
    if (t == 0) v = cls_token[d] + player_emb[ptm * DD + d];
    else        v = cell_emb[board[b * 42 + (t - 1)] * DD + d];
    sm.xb[t][d] = v;
  }
  __syncthreads();

  // LN (f32 stats from xb) -> yb bf16
  auto layer_norm = [&](const float* s, const float* bb) {
    for (int t = wave; t < TS; t += 4) {
      float a0 = sm.xb[t][lane], a1 = sm.xb[t][lane + 64];
      float sum = wsum(a0 + a1);
      float sq  = wsum(a0 * a0 + a1 * a1);
      float mu  = sum * (1.0f / 128.0f);
      float var = sq * (1.0f / 128.0f) - mu * mu;
      float r   = rsqrtf(var + 1e-5f);
      sm.yb[t][lane]      = (__bf16)((a0 - mu) * r * s[lane]      + bb[lane]);
      sm.yb[t][lane + 64] = (__bf16)((a1 - mu) * r * s[lane + 64] + bb[lane + 64]);
    }
    // zero pad rows 43..47 (feed MFMA A-frags)
    for (int idx = tid; idx < 5 * 136; idx += 256)
      sm.yb[43 + idx / 136][idx % 136] = (__bf16)0.f;
  };

  // A·B accumulate: af rows from LDS, B-frags from global W^T (row stride 128)
  auto gemmNT2 = [&](const bf16x8_t (&af)[3][4], const __bf16* WT, f32x4_t (&acc)[3][2]) {
    #pragma unroll
    for (int nt = 0; nt < 2; ++nt) {
      #pragma unroll
      for (int kk = 0; kk < 4; ++kk) {
        bf16x8_t bfrag = *(const bf16x8_t*)(WT + (wave * 32 + nt * 16 + l15) * DD + kk * 32 + hi8);
        #pragma unroll
        for (int m = 0; m < 3; ++m)
          acc[m][nt] = MFMA16(af[m][kk], bfrag, acc[m][nt]);
      }
    }
  };

  for (int l = 0; l < NLAY; ++l) {
    const __bf16* WqT = ws + l * 16384;
    const __bf16* WkT = ws + 65536  + l * 16384;
    const __bf16* WvT = ws + 131072 + l * 16384;
    const __bf16* WoT = ws + 196608 + l * 16384;
    const __bf16* W1T = ws + 262144 + l * 65536;
    const __bf16* W2T = ws + 524288 + l * 65536;
    const float* bq_l = bq + l * DD;
    const float* bk_l = bk + l * DD;
    const float* bv_l = bv + l * DD;
    const float* bo_l = bo + l * DD;
    const float* b1_l = b1 + l * DFFN;
    const float* b2_l = b2 + l * DD;

    // ---- LN1 ----
    layer_norm(ln1_s + l * DD, ln1_b + l * DD);
    // zero Vt pad key-columns 48..71 (PV reads k up to 63; avoid 0*NaN)
    for (int idx = tid; idx < 128 * 24; idx += 256)
      sm.u.a.Vt[idx / 24][48 + idx % 24] = (__bf16)0.f;
    __syncthreads();

    // ---- QKV projections (MFMA) ----
    {
      bf16x8_t af[3][4];
      #pragma unroll
      for (int m = 0; m < 3; ++m) {
        #pragma unroll
        for (int kk = 0; kk < 4; ++kk)
          af[m][kk] = *(const bf16x8_t*)(&sm.yb[m * 16 + l15][kk * 32 + hi8]);
      }

      { // Q
        f32x4_t acc[3][2] = {};
        gemmNT2(af, WqT, acc);
        #pragma unroll
        for (int nt = 0; nt < 2; ++nt) {
          int col = wave * 32 + nt * 16 + l15;
          float bvv = bq_l[col];
          #pragma unroll
          for (int m = 0; m < 3; ++m) {
            #pragma unroll
            for (int r = 0; r < 4; ++r)
              sm.u.a.Qb[m * 16 + hi4 + r][col] = (__bf16)(acc[m][nt][r] + bvv);
          }
        }
      }
      { // K
        f32x4_t acc[3][2] = {};
        gemmNT2(af, WkT, acc);
        #pragma unroll
        for (int nt = 0; nt < 2; ++nt) {
          int col = wave * 32 + nt * 16 + l15;
          float bvv = bk_l[col];
          #pragma unroll
          for (int m = 0; m < 3; ++m) {
            #pragma unroll
            for (int r = 0; r < 4; ++r)
              sm.u.a.Kb[m * 16 + hi4 + r][col] = (__bf16)(acc[m][nt][r] + bvv);
          }
        }
      }
      { // V -> transposed store Vt[d][token]
        f32x4_t acc[3][2] = {};
        gemmNT2(af, WvT, acc);
        #pragma unroll
        for (int nt = 0; nt < 2; ++nt) {
          int col = wave * 32 + nt * 16 + l15;     // output dim d
          float bvv = bv_l[col];
          #pragma unroll
          for (int m = 0; m < 3; ++m) {
            #pragma unroll
            for (int r = 0; r < 4; ++r)
              sm.u.a.Vt[col][m * 16 + hi4 + r] = (__bf16)(acc[m][nt][r] + bvv);
          }
        }
      }
    }
    __syncthreads();

    // ---- attention: wave = head. QK^T -> softmax -> PV. No intra-phase barriers:
    // each wave only touches its own head's columns of Qb/Kb/Vt/P.
    {
      const int h = wave;
      // QK^T: A=Q rows, B=K rows (K^T as B via row-major K)
      bf16x8_t qa[3], kb[3];
      #pragma unroll
      for (int m = 0; m < 3; ++m)
        qa[m] = *(const bf16x8_t*)(&sm.u.a.Qb[m * 16 + l15][h * 32 + hi8]);
      #pragma unroll
      for (int nt = 0; nt < 3; ++nt)
        kb[nt] = *(const bf16x8_t*)(&sm.u.a.Kb[nt * 16 + l15][h * 32 + hi8]);
      f32x4_t sc[3][3] = {};
      #pragma unroll
      for (int m = 0; m < 3; ++m) {
        #pragma unroll
        for (int nt = 0; nt < 3; ++nt)
          sc[m][nt] = MFMA16(qa[m], kb[nt], sc[m][nt]);
      }

      // bias + mask + softmax (row lives across the 16 lanes of its quarter-wave)
      const float scl = 0.17677669529663687f;  // 1/sqrt(32)
      float ev[3][3][4];
      float lmax[3][4], lsum[3][4];
      #pragma unroll
      for (int m = 0; m < 3; ++m) {
        #pragma unroll
        for (int r = 0; r < 4; ++r) lmax[m][r] = -1e30f;
      }
      #pragma unroll
      for (int m = 0; m < 3; ++m) {
        #pragma unroll
        for (int nt = 0; nt < 3; ++nt) {
          int kcol = nt * 16 + l15;
          #pragma unroll
          for (int r = 0; r < 4; ++r) {
            int q = m * 16 + hi4 + r;
            int qc = q > 42 ? 42 : q;
            float v;
            if (kcol <= 42)
              v = sc[m][nt][r] * scl + sm.bias[h][sm.bucket[qc][kcol]];
            else
              v = -1e30f;
            ev[m][nt][r] = v;
            lmax[m][r] = fmaxf(lmax[m][r], v);
          }
        }
      }
      #pragma unroll
      for (int m = 0; m < 3; ++m) {
        #pragma unroll
        for (int r = 0; r < 4; ++r) {
          lmax[m][r] = red16max(lmax[m][r]);
          lsum[m][r] = 0.f;
        }
      }
      #pragma unroll
      for (int m = 0; m < 3; ++m) {
        #pragma unroll
        for (int nt = 0; nt < 3; ++nt) {
          int kcol = nt * 16 + l15;
          #pragma unroll
          for (int r = 0; r < 4; ++r) {
            float e = (kcol <= 42) ? expf(ev[m][nt][r] - lmax[m][r]) : 0.f;
            ev[m][nt][r] = e;
            lsum[m][r] += e;
          }
        }
      }
      #pragma unroll
      for (int m = 0; m < 3; ++m) {
        #pragma unroll
        for (int r = 0; r < 4; ++r)
          lsum[m][r] = 1.0f / red16sum(lsum[m][r]);
      }
      #pragma unroll
      for (int m = 0; m < 3; ++m) {
        #pragma unroll
        for (int nt = 0; nt < 3; ++nt) {
          #pragma unroll
          for (int r = 0; r < 4; ++r)
            sm.u.a.P[h][m * 16 + hi4 + r][nt * 16 + l15] =
                (__bf16)(ev[m][nt][r] * lsum[m][r]);
        }
      }
      // zero P pad key-columns 48..63
      for (int i = lane; i < 48 * 16; i += 64)
        sm.u.a.P[h][i >> 4][48 + (i & 15)] = (__bf16)0.f;

      // PV: A=P rows (k=key), B=Vt rows (d), accumulate attn-out
      f32x4_t oacc[3][2] = {};
      #pragma unroll
      for (int ks = 0; ks < 2; ++ks) {
        bf16x8_t pa[3], vb[2];
        #pragma unroll
        for (int m = 0; m < 3; ++m)
          pa[m] = *(const bf16x8_t*)(&sm.u.a.P[h][m * 16 + l15][ks * 32 + hi8]);
        #pragma unroll
        for (int nt = 0; nt < 2; ++nt)
          vb[nt] = *(const bf16x8_t*)(&sm.u.a.Vt[h * 32 + nt * 16 + l15][ks * 32 + hi8]);
        #pragma unroll
        for (int m = 0; m < 3; ++m) {
          #pragma unroll
          for (int nt = 0; nt < 2; ++nt)
            oacc[m][nt] = MFMA16(pa[m], vb[nt], oacc[m][nt]);
        }
      }
      // store attn-out into Kb (this head's columns; K already consumed)
      #pragma unroll
      for (int nt = 0; nt < 2; ++nt) {
        int col = h * 32 + nt * 16 + l15;
        #pragma unroll
        for (int m = 0; m < 3; ++m) {
          #pragma unroll
          for (int r = 0; r < 4; ++r)
            sm.u.a.Kb[m * 16 + hi4 + r][col] = (__bf16)(oacc[m][nt][r]);
        }
      }
    }
    __syncthreads();

    // ---- O projection + residual into xb ----
    {
      bf16x8_t af[3][4];
      #pragma unroll
      for (int m = 0; m < 3; ++m) {
        #pragma unroll
        for (int kk = 0; kk < 4; ++kk)
          af[m][kk] = *(const bf16x8_t*)(&sm.u.a.Kb[m * 16 + l15][kk * 32 + hi8]);
      }
      f32x4_t acc[3][2] = {};
      gemmNT2(af, WoT, acc);
      #pragma unroll
      for (int nt = 0; nt < 2; ++nt) {
        int col = wave * 32 + nt * 16 + l15;
        float bvv = bo_l[col];
        #pragma unroll
        for (int m = 0; m < 3; ++m) {
          #pragma unroll
          for (int r = 0; r < 4; ++r) {
            int row = m * 16 + hi4 + r;
            if (row < TS) sm.xb[row][col] += acc[m][nt][r] + bvv;
          }
        }
      }
    }
    __syncthreads();

    // ---- LN2 ----
    layer_norm(ln2_s + l * DD, ln2_b + l * DD);
    __syncthreads();

    // ---- FFN A: gbuf = gelu(yb @ W1 + b1), wave owns 8 N-tiles ----
    {
      bf16x8_t af[3][4];
      #pragma unroll
      for (int m = 0; m < 3; ++m) {
        #pragma unroll
        for (int kk = 0; kk < 4; ++kk)
          af[m][kk] = *(const bf16x8_t*)(&sm.yb[m * 16 + l15][kk * 32 + hi8]);
      }
      #pragma unroll
      for (int nc = 0; nc < 4; ++nc) {
        f32x4_t acc[3][2] = {};
        #pragma unroll
        for (int nt = 0; nt < 2; ++nt) {
          int nrow = (wave * 8 + nc * 2 + nt) * 16 + l15;
          #pragma unroll
          for (int kk = 0; kk < 4; ++kk) {
            bf16x8_t bfrag = *(const bf16x8_t*)(W1T + nrow * DD + kk * 32 + hi8);
            #pragma unroll
            for (int m = 0; m < 3; ++m)
              acc[m][nt] = MFMA16(af[m][kk], bfrag, acc[m][nt]);
          }
        }
        #pragma unroll
        for (int nt = 0; nt < 2; ++nt) {
          int col = (wave * 8 + nc * 2 + nt) * 16 + l15;
          float bvv = b1_l[col];
          #pragma unroll
          for (int m = 0; m < 3; ++m) {
            #pragma unroll
            for (int r = 0; r < 4; ++r)
              sm.u.f.gbuf[m * 16 + hi4 + r][col] = (__bf16)gelu_exact(acc[m][nt][r] + bvv);
          }
        }
      }
    }
    __syncthreads();

    // ---- FFN B: xb += gbuf @ W2 + b2 ----
    {
      f32x4_t acc[3][2] = {};
      for (int ks = 0; ks < 16; ++ks) {
        bf16x8_t ga[3], wb[2];
        #pragma unroll
        for (int m = 0; m < 3; ++m)
          ga[m] = *(const bf16x8_t*)(&sm.u.f.gbuf[m * 16 + l15][ks * 32 + hi8]);
        #pragma unroll
        for (int nt = 0; nt < 2; ++nt)
          wb[nt] = *(const bf16x8_t*)(W2T + (wave * 32 + nt * 16 + l15) * DFFN + ks * 32 + hi8);
        #pragma unroll
        for (int m = 0; m < 3; ++m) {
          #pragma unroll
          for (int nt = 0; nt < 2; ++nt)
            acc[m][nt] = MFMA16(ga[m], wb[nt], acc[m][nt]);
        }
      }
      #pragma unroll
      for (int nt = 0; nt < 2; ++nt) {
        int col = wave * 32 + nt * 16 + l15;
        float bvv = b2_l[col];
        #pragma unroll
        for (int m = 0; m < 3; ++m) {
          #pragma unroll
          for (int r = 0; r < 4; ++r) {
            int row = m * 16 + hi4 + r;
            if (row < TS) sm.xb[row][col] += acc[m][nt][r] + bvv;
          }
        }
      }
    }
    __syncthreads();
  }

  // ---- final LN (token 0) -> yb[0] bf16 ----
  if (wave == 0) {
    float a0 = sm.xb[0][lane], a1 = sm.xb[0][lane + 64];
    float sum = wsum(a0 + a1);
    float sq  = wsum(a0 * a0 + a1 * a1);
    float mu  = sum * (1.0f / 128.0f);
    float var = sq * (1.0f / 128.0f) - mu * mu;
    float r   = rsqrtf(var + 1e-5f);
    sm.yb[0][lane]      = (__bf16)((a0 - mu) * r * lnf_s[lane]      + lnf_b[lane]);
    sm.yb[0][lane + 64] = (__bf16)((a1 - mu) * r * lnf_s[lane + 64] + lnf_b[lane + 64]);
  }
  __syncthreads();

  // ---- head + masking ----
  if (tid < 7) {
    const int c = tid;
    float acc = bhead[c];
    for (int d = 0; d < DD; ++d) acc += (float)sm.yb[0][d] * Whead[d * 7 + c];
    const int ob = b * 7 + c;
    const bool valid = (board[b * 42 + c] == 0);  // board row 0
    out[ob] = acc;
    out[nB * 7 + ob] = valid ? acc : -1e9f;
    out[2 * nB * 7 + ob] = valid ? 1.0f : 0.0f;
  }
}

extern "C" void kernel_launch(void* const* d_in, const int* in_sizes, int n_in,
                              void* d_out, int out_size, void* d_ws, size_t ws_size,
                              hipStream_t stream) {
  const int*   board      = (const int*)d_in[0];
  const int*   ptm        = (const int*)d_in[1];
  const int*   bucket_idx = (const int*)d_in[2];
  const float* cell_emb   = (const float*)d_in[3];
  const float* player_emb = (const float*)d_in[4];
  const float* cls_token  = (const float*)d_in[5];
  const float* bias_table = (const float*)d_in[6];
  const float* ln1_s      = (const float*)d_in[7];
  const float* ln1_b      = (const float*)d_in[8];
  const float* Wq         = (const float*)d_in[9];
  const float* bq         = (const float*)d_in[10];
  const float* Wk         = (const float*)d_in[11];
  const float* bk         = (const float*)d_in[12];
  const float* Wv         = (const float*)d_in[13];
  const float* bv         = (const float*)d_in[14];
  const float* Wo         = (const float*)d_in[15];
  const float* bo         = (const float*)d_in[16];
  const float* ln2_s      = (const float*)d_in[17];
  const float* ln2_b      = (const float*)d_in[18];
  const float* W1         = (const float*)d_in[19];
  const float* b1         = (const float*)d_in[20];
  const float* W2         = (const float*)d_in[21];
  const float* b2         = (const float*)d_in[22];
  const float* lnf_s      = (const float*)d_in[23];
  const float* lnf_b      = (const float*)d_in[24];
  const float* Whead      = (const float*)d_in[25];
  const float* bhead      = (const float*)d_in[26];

  const int nB = in_sizes[1];  // 4096
  float* out = (float*)d_out;
  __bf16* ws = (__bf16*)d_ws;  // needs 786432*2 = 1.57 MB

  hipLaunchKernelGGL(prep_weights, dim3(3072), dim3(256), 0, stream,
                     Wq, Wk, Wv, Wo, W1, W2, ws);
  hipLaunchKernelGGL(tdqn_fused, dim3(nB), dim3(256), 0, stream,
                     board, ptm, bucket_idx, cell_emb, player_emb, cls_token,
                     bias_table, ln1_s, ln1_b, bq, bk, bv, bo,
                     ln2_s, ln2_b, b1, b2, lnf_s, lnf_b, Whead, bhead,
                     ws, out, nB);
}

// Round 7
// 1731.564 us; speedup vs baseline: 9.0528x; 1.3034x over previous
//
#include <hip/hip_runtime.h>
#include <math.h>

#define TS 43      // tokens per sample (1 + 6*7)
#define DD 128
#define NH 4
#define DFFN 512
#define NLAY 4
#define NT_THREADS 512

typedef __bf16 bf16x8_t __attribute__((ext_vector_type(8)));
typedef float  f32x4_t  __attribute__((ext_vector_type(4)));

#define MFMA16(a, b, c) __builtin_amdgcn_mfma_f32_16x16x32_bf16((a), (b), (c), 0, 0, 0)

// LDS layout. All fragment-read buffers have 16B-aligned row strides.
struct __align__(16) SmemT {
  float  xb[48][132];            // residual stream, f32
  __bf16 yb[48][136];            // LN output (MFMA A input)
  union {
    struct {
      __bf16 Qb[48][136];        // Q (A-operand for QK^T)
      __bf16 Kb[48][136];        // K (B-operand for QK^T); reused for attn-out
      __bf16 Vt[128][72];        // V transposed: Vt[d][token] (B-operand for PV)
      __bf16 P[NH][48][72];      // probs per head (A-operand for PV)
    } a;
    struct { __bf16 gbuf[48][520]; } f;   // FFN intermediate
  } u;
  float bias[NH][144];
  int   bucket[TS][44];
};

__device__ __forceinline__ float wsum(float v) {
  #pragma unroll
  for (int m = 32; m >= 1; m >>= 1) v += __shfl_xor(v, m, 64);
  return v;
}
__device__ __forceinline__ float red16max(float v) {
  #pragma unroll
  for (int m = 8; m >= 1; m >>= 1) v = fmaxf(v, __shfl_xor(v, m, 64));
  return v;
}
__device__ __forceinline__ float red16sum(float v) {
  #pragma unroll
  for (int m = 8; m >= 1; m >>= 1) v += __shfl_xor(v, m, 64);
  return v;
}
__device__ __forceinline__ float gelu_exact(float x) {
  return 0.5f * x * (1.0f + erff(x * 0.70710678118654752f));
}

// ---- weight prep: f32 [K][N] -> bf16 W^T [N][K] in d_ws ----
__global__ void prep_weights(const float* __restrict__ Wq, const float* __restrict__ Wk,
                             const float* __restrict__ Wv, const float* __restrict__ Wo,
                             const float* __restrict__ W1, const float* __restrict__ W2,
                             __bf16* __restrict__ ws) {
  int idx = blockIdx.x * 256 + threadIdx.x;
  if (idx < 262144) {
    int t = idx >> 16;            // 0..3 : q,k,v,o
    int rem = idx & 65535;
    int l = rem >> 14;
    int r2 = rem & 16383;
    int n = r2 >> 7, k = r2 & 127;
    const float* W = (t == 0) ? Wq : (t == 1) ? Wk : (t == 2) ? Wv : Wo;
    ws[idx] = (__bf16)W[l * 16384 + k * 128 + n];
  } else if (idx < 524288) {
    int rem = idx - 262144;       // W1T: [512][128] per layer
    int l = rem >> 16;
    int r2 = rem & 65535;
    int n = r2 >> 7, k = r2 & 127;
    ws[idx] = (__bf16)W1[l * 65536 + k * 512 + n];
  } else if (idx < 786432) {
    int rem = idx - 524288;       // W2T: [128][512] per layer
    int l = rem >> 16;
    int r2 = rem & 65535;
    int n = r2 >> 9, f = r2 & 511;
    ws[idx] = (__bf16)W2[l * 65536 + f * 128 + n];
  }
}

__global__ __launch_bounds__(NT_THREADS, 2)
void tdqn_fused(const int* __restrict__ board, const int* __restrict__ ptm_arr,
                const int* __restrict__ bucket_index,
                const float* __restrict__ cell_emb, const float* __restrict__ player_emb,
                const float* __restrict__ cls_token, const float* __restrict__ bias_table,
                const float* __restrict__ ln1_s, const float* __restrict__ ln1_b,
                const float* __restrict__ bq, const float* __restrict__ bk,
                const float* __restrict__ bv, const float* __restrict__ bo,
                const float* __restrict__ ln2_s, const float* __restrict__ ln2_b,
                const float* __restrict__ b1, const float* __restrict__ b2,
                const float* __restrict__ lnf_s, const float* __restrict__ lnf_b,
                const float* __restrict__ Whead, const float* __restrict__ bhead,
                const __bf16* __restrict__ ws,
                float* __restrict__ out, int nB)
{
  __shared__ SmemT sm;
  const int b = blockIdx.x;
  const int tid = threadIdx.x;
  const int lane = tid & 63;
  const int wave = tid >> 6;         // 0..7
  const int l15 = lane & 15;
  const int hi8 = (lane >> 4) * 8;   // k-offset within fragment
  const int hi4 = (lane >> 4) * 4;   // row-offset within D tile

  // ---- stage bucket + bias tables ----
  for (int idx = tid; idx < TS * TS; idx += NT_THREADS)
    sm.bucket[idx / TS][idx % TS] = bucket_index[idx];
  for (int idx = tid; idx < NH * 143; idx += NT_THREADS)
    sm.bias[idx / 143][idx % 143] = bias_table[idx];

  // ---- embeddings (f32 residual) ----
  const int ptm = ptm_arr[b];
  for (int idx = tid; idx < TS * DD; idx += NT_THREADS) {
    int t = idx >> 7, d = idx & 127;
    float v;
    if (t == 0) v = cls_token[d] + player_emb[ptm * DD + d];
    else        v = cell_emb[board[b * 42 + (t - 1)] * DD + d];
    sm.xb[t][d] = v;
  }
  __syncthreads();

  // LN (f32 stats from xb) -> yb bf16
  auto layer_norm = [&](const float* s, const float* bb) {
    for (int t = wave; t < TS; t += 8) {
      float a0 = sm.xb[t][lane], a1 = sm.xb[t][lane + 64];
      float sum = wsum(a0 + a1);
      float sq  = wsum(a0 * a0 + a1 * a1);
      float mu  = sum * (1.0f / 128.0f);
      float var = sq * (1.0f / 128.0f) - mu * mu;
      float r   = rsqrtf(var + 1e-5f);
      sm.yb[t][lane]      = (__bf16)((a0 - mu) * r * s[lane]      + bb[lane]);
      sm.yb[t][lane + 64] = (__bf16)((a1 - mu) * r * s[lane + 64] + bb[lane + 64]);
    }
    // zero pad rows 43..47 (feed MFMA A-frags)
    for (int idx = tid; idx < 5 * 136; idx += NT_THREADS)
      sm.yb[43 + idx / 136][idx % 136] = (__bf16)0.f;
  };

  // 48x128 @ 128x16 tile: af rows from LDS, B-frags from global W^T row nrow
  auto gemmNT1 = [&](const bf16x8_t (&af)[3][4], const __bf16* WT, int nrow,
                     f32x4_t (&acc)[3]) {
    #pragma unroll
    for (int kk = 0; kk < 4; ++kk) {
      bf16x8_t bfrag = *(const bf16x8_t*)(WT + nrow * DD + kk * 32 + hi8);
      #pragma unroll
      for (int m = 0; m < 3; ++m)
        acc[m] = MFMA16(af[m][kk], bfrag, acc[m]);
    }
  };

  for (int l = 0; l < NLAY; ++l) {
    const __bf16* WqT = ws + l * 16384;
    const __bf16* WkT = ws + 65536  + l * 16384;
    const __bf16* WvT = ws + 131072 + l * 16384;
    const __bf16* WoT = ws + 196608 + l * 16384;
    const __bf16* W1T = ws + 262144 + l * 65536;
    const __bf16* W2T = ws + 524288 + l * 65536;
    const float* bq_l = bq + l * DD;
    const float* bk_l = bk + l * DD;
    const float* bv_l = bv + l * DD;
    const float* bo_l = bo + l * DD;
    const float* b1_l = b1 + l * DFFN;
    const float* b2_l = b2 + l * DD;

    // ---- LN1 ----
    layer_norm(ln1_s + l * DD, ln1_b + l * DD);
    // zero Vt pad key-columns 48..71 (PV reads k up to 63; avoid 0*NaN)
    for (int idx = tid; idx < 128 * 24; idx += NT_THREADS)
      sm.u.a.Vt[idx / 24][48 + idx % 24] = (__bf16)0.f;
    __syncthreads();

    // ---- QKV projections (MFMA): each wave owns 16 output cols ----
    {
      bf16x8_t af[3][4];
      #pragma unroll
      for (int m = 0; m < 3; ++m) {
        #pragma unroll
        for (int kk = 0; kk < 4; ++kk)
          af[m][kk] = *(const bf16x8_t*)(&sm.yb[m * 16 + l15][kk * 32 + hi8]);
      }
      const int nrow = wave * 16 + l15;
      const int col  = nrow;

      { // Q
        f32x4_t acc[3] = {};
        gemmNT1(af, WqT, nrow, acc);
        float bvv = bq_l[col];
        #pragma unroll
        for (int m = 0; m < 3; ++m) {
          #pragma unroll
          for (int r = 0; r < 4; ++r)
            sm.u.a.Qb[m * 16 + hi4 + r][col] = (__bf16)(acc[m][r] + bvv);
        }
      }
      { // K
        f32x4_t acc[3] = {};
        gemmNT1(af, WkT, nrow, acc);
        float bvv = bk_l[col];
        #pragma unroll
        for (int m = 0; m < 3; ++m) {
          #pragma unroll
          for (int r = 0; r < 4; ++r)
            sm.u.a.Kb[m * 16 + hi4 + r][col] = (__bf16)(acc[m][r] + bvv);
        }
      }
      { // V -> transposed store Vt[d][token]
        f32x4_t acc[3] = {};
        gemmNT1(af, WvT, nrow, acc);
        float bvv = bv_l[col];
        #pragma unroll
        for (int m = 0; m < 3; ++m) {
          #pragma unroll
          for (int r = 0; r < 4; ++r)
            sm.u.a.Vt[col][m * 16 + hi4 + r] = (__bf16)(acc[m][r] + bvv);
        }
      }
    }
    __syncthreads();

    // ---- QK^T + softmax: waves 0..3, one head each ----
    if (wave < NH) {
      const int h = wave;
      bf16x8_t qa[3], kb[3];
      #pragma unroll
      for (int m = 0; m < 3; ++m)
        qa[m] = *(const bf16x8_t*)(&sm.u.a.Qb[m * 16 + l15][h * 32 + hi8]);
      #pragma unroll
      for (int nt = 0; nt < 3; ++nt)
        kb[nt] = *(const bf16x8_t*)(&sm.u.a.Kb[nt * 16 + l15][h * 32 + hi8]);
      f32x4_t sc[3][3] = {};
      #pragma unroll
      for (int m = 0; m < 3; ++m) {
        #pragma unroll
        for (int nt = 0; nt < 3; ++nt)
          sc[m][nt] = MFMA16(qa[m], kb[nt], sc[m][nt]);
      }

      const float scl = 0.17677669529663687f;  // 1/sqrt(32)
      float ev[3][3][4];
      float lmax[3][4], lsum[3][4];
      #pragma unroll
      for (int m = 0; m < 3; ++m) {
        #pragma unroll
        for (int r = 0; r < 4; ++r) lmax[m][r] = -1e30f;
      }
      #pragma unroll
      for (int m = 0; m < 3; ++m) {
        #pragma unroll
        for (int nt = 0; nt < 3; ++nt) {
          int kcol = nt * 16 + l15;
          #pragma unroll
          for (int r = 0; r < 4; ++r) {
            int q = m * 16 + hi4 + r;
            int qc = q > 42 ? 42 : q;
            float v;
            if (kcol <= 42)
              v = sc[m][nt][r] * scl + sm.bias[h][sm.bucket[qc][kcol]];
            else
              v = -1e30f;
            ev[m][nt][r] = v;
            lmax[m][r] = fmaxf(lmax[m][r], v);
          }
        }
      }
      #pragma unroll
      for (int m = 0; m < 3; ++m) {
        #pragma unroll
        for (int r = 0; r < 4; ++r) {
          lmax[m][r] = red16max(lmax[m][r]);
          lsum[m][r] = 0.f;
        }
      }
      #pragma unroll
      for (int m = 0; m < 3; ++m) {
        #pragma unroll
        for (int nt = 0; nt < 3; ++nt) {
          int kcol = nt * 16 + l15;
          #pragma unroll
          for (int r = 0; r < 4; ++r) {
            float e = (kcol <= 42) ? expf(ev[m][nt][r] - lmax[m][r]) : 0.f;
            ev[m][nt][r] = e;
            lsum[m][r] += e;
          }
        }
      }
      #pragma unroll
      for (int m = 0; m < 3; ++m) {
        #pragma unroll
        for (int r = 0; r < 4; ++r)
          lsum[m][r] = 1.0f / red16sum(lsum[m][r]);
      }
      #pragma unroll
      for (int m = 0; m < 3; ++m) {
        #pragma unroll
        for (int nt = 0; nt < 3; ++nt) {
          #pragma unroll
          for (int r = 0; r < 4; ++r)
            sm.u.a.P[h][m * 16 + hi4 + r][nt * 16 + l15] =
                (__bf16)(ev[m][nt][r] * lsum[m][r]);
        }
      }
      // zero P pad key-columns 48..63
      for (int i = lane; i < 48 * 16; i += 64)
        sm.u.a.P[h][i >> 4][48 + (i & 15)] = (__bf16)0.f;
    }
    __syncthreads();

    // ---- PV: 8 waves, wave = head*2 + d-half ----
    {
      const int h = wave >> 1, ntv = wave & 1;
      f32x4_t oacc[3] = {};
      #pragma unroll
      for (int ks = 0; ks < 2; ++ks) {
        bf16x8_t pa[3], vb;
        #pragma unroll
        for (int m = 0; m < 3; ++m)
          pa[m] = *(const bf16x8_t*)(&sm.u.a.P[h][m * 16 + l15][ks * 32 + hi8]);
        vb = *(const bf16x8_t*)(&sm.u.a.Vt[h * 32 + ntv * 16 + l15][ks * 32 + hi8]);
        #pragma unroll
        for (int m = 0; m < 3; ++m)
          oacc[m] = MFMA16(pa[m], vb, oacc[m]);
      }
      // store attn-out into Kb cols wave*16+l15 (K already consumed)
      const int col = wave * 16 + l15;
      #pragma unroll
      for (int m = 0; m < 3; ++m) {
        #pragma unroll
        for (int r = 0; r < 4; ++r)
          sm.u.a.Kb[m * 16 + hi4 + r][col] = (__bf16)(oacc[m][r]);
      }
    }
    __syncthreads();

    // ---- O projection + residual into xb ----
    {
      bf16x8_t af[3][4];
      #pragma unroll
      for (int m = 0; m < 3; ++m) {
        #pragma unroll
        for (int kk = 0; kk < 4; ++kk)
          af[m][kk] = *(const bf16x8_t*)(&sm.u.a.Kb[m * 16 + l15][kk * 32 + hi8]);
      }
      f32x4_t acc[3] = {};
      const int nrow = wave * 16 + l15;
      gemmNT1(af, WoT, nrow, acc);
      const int col = nrow;
      float bvv = bo_l[col];
      #pragma unroll
      for (int m = 0; m < 3; ++m) {
        #pragma unroll
        for (int r = 0; r < 4; ++r) {
          int row = m * 16 + hi4 + r;
          if (row < TS) sm.xb[row][col] += acc[m][r] + bvv;
        }
      }
    }
    __syncthreads();

    // ---- LN2 ----
    layer_norm(ln2_s + l * DD, ln2_b + l * DD);
    __syncthreads();

    // ---- FFN A: gbuf = gelu(yb @ W1 + b1); wave owns 64 cols (4 tiles) ----
    {
      bf16x8_t af[3][4];
      #pragma unroll
      for (int m = 0; m < 3; ++m) {
        #pragma unroll
        for (int kk = 0; kk < 4; ++kk)
          af[m][kk] = *(const bf16x8_t*)(&sm.yb[m * 16 + l15][kk * 32 + hi8]);
      }
      #pragma unroll
      for (int cc = 0; cc < 4; ++cc) {
        f32x4_t acc[3] = {};
        const int nrow = wave * 64 + cc * 16 + l15;
        gemmNT1(af, W1T, nrow, acc);
        const int col = nrow;
        float bvv = b1_l[col];
        #pragma unroll
        for (int m = 0; m < 3; ++m) {
          #pragma unroll
          for (int r = 0; r < 4; ++r)
            sm.u.f.gbuf[m * 16 + hi4 + r][col] = (__bf16)gelu_exact(acc[m][r] + bvv);
        }
      }
    }
    __syncthreads();

    // ---- FFN B: xb += gbuf @ W2 + b2; wave owns 16 output cols ----
    {
      f32x4_t acc[3] = {};
      const int nrow = wave * 16 + l15;
      for (int ks = 0; ks < 16; ++ks) {
        bf16x8_t ga[3], wb;
        #pragma unroll
        for (int m = 0; m < 3; ++m)
          ga[m] = *(const bf16x8_t*)(&sm.u.f.gbuf[m * 16 + l15][ks * 32 + hi8]);
        wb = *(const bf16x8_t*)(W2T + nrow * DFFN + ks * 32 + hi8);
        #pragma unroll
        for (int m = 0; m < 3; ++m)
          acc[m] = MFMA16(ga[m], wb, acc[m]);
      }
      const int col = nrow;
      float bvv = b2_l[col];
      #pragma unroll
      for (int m = 0; m < 3; ++m) {
        #pragma unroll
        for (int r = 0; r < 4; ++r) {
          int row = m * 16 + hi4 + r;
          if (row < TS) sm.xb[row][col] += acc[m][r] + bvv;
        }
      }
    }
    __syncthreads();
  }

  // ---- final LN (token 0) -> yb[0] bf16 ----
  if (wave == 0) {
    float a0 = sm.xb[0][lane], a1 = sm.xb[0][lane + 64];
    float sum = wsum(a0 + a1);
    float sq  = wsum(a0 * a0 + a1 * a1);
    float mu  = sum * (1.0f / 128.0f);
    float var = sq * (1.0f / 128.0f) - mu * mu;
    float r   = rsqrtf(var + 1e-5f);
    sm.yb[0][lane]      = (__bf16)((a0 - mu) * r * lnf_s[lane]      + lnf_b[lane]);
    sm.yb[0][lane + 64] = (__bf16)((a1 - mu) * r * lnf_s[lane + 64] + lnf_b[lane + 64]);
  }
  __syncthreads();

  // ---- head + masking ----
  if (tid < 7) {
    const int c = tid;
    float acc = bhead[c];
    for (int d = 0; d < DD; ++d) acc += (float)sm.yb[0][d] * Whead[d * 7 + c];
    const int ob = b * 7 + c;
    const bool valid = (board[b * 42 + c] == 0);  // board row 0
    out[ob] = acc;
    out[nB * 7 + ob] = valid ? acc : -1e9f;
    out[2 * nB * 7 + ob] = valid ? 1.0f : 0.0f;
  }
}

extern "C" void kernel_launch(void* const* d_in, const int* in_sizes, int n_in,
                              void* d_out, int out_size, void* d_ws, size_t ws_size,
                              hipStream_t stream) {
  const int*   board      = (const int*)d_in[0];
  const int*   ptm        = (const int*)d_in[1];
  const int*   bucket_idx = (const int*)d_in[2];
  const float* cell_emb   = (const float*)d_in[3];
  const float* player_emb = (const float*)d_in[4];
  const float* cls_token  = (const float*)d_in[5];
  const float* bias_table = (const float*)d_in[6];
  const float* ln1_s      = (const float*)d_in[7];
  const float* ln1_b      = (const float*)d_in[8];
  const float* Wq         = (const float*)d_in[9];
  const float* bq         = (const float*)d_in[10];
  const float* Wk         = (const float*)d_in[11];
  const float* bk         = (const float*)d_in[12];
  const float* Wv         = (const float*)d_in[13];
  const float* bv         = (const float*)d_in[14];
  const float* Wo         = (const float*)d_in[15];
  const float* bo         = (const float*)d_in[16];
  const float* ln2_s      = (const float*)d_in[17];
  const float* ln2_b      = (const float*)d_in[18];
  const float* W1         = (const float*)d_in[19];
  const float* b1         = (const float*)d_in[20];
  const float* W2         = (const float*)d_in[21];
  const float* b2         = (const float*)d_in[22];
  const float* lnf_s      = (const float*)d_in[23];
  const float* lnf_b      = (const float*)d_in[24];
  const float* Whead      = (const float*)d_in[25];
  const float* bhead      = (const float*)d_in[26];

  const int nB = in_sizes[1];  // 4096
  float* out = (float*)d_out;
  __bf16* ws = (__bf16*)d_ws;  // needs 786432*2 = 1.57 MB

  hipLaunchKernelGGL(prep_weights, dim3(3072), dim3(256), 0, stream,
                     Wq, Wk, Wv, Wo, W1, W2, ws);
  hipLaunchKernelGGL(tdqn_fused, dim3(nB), dim3(NT_THREADS), 0, stream,
                     board, ptm, bucket_idx, cell_emb, player_emb, cls_token,
                     bias_table, ln1_s, ln1_b, bq, bk, bv, bo,
                     ln2_s, ln2_b, b1, b2, lnf_s, lnf_b, Whead, bhead,
                     ws, out, nB);
}